// Round 2
// baseline (403.426 us; speedup 1.0000x reference)
//
#include <hip/hip_runtime.h>
#include <math.h>

#define NB_ 512
#define B_ 32
#define H_ 16
#define D_ 576
#define KV_ 512
#define BS_ 128
#define STR 580                       // padded LDS row stride (floats); 580%32=4 breaks bank aliasing
#define SCALE_ 0.07216878364870323f   // 192^-0.5

// Workspace as device globals: k1 fully writes before k2 reads, every call.
__device__ float g_o[NB_ * H_ * KV_];   // unscaled per-block output, 16.8 MB
__device__ float g_bm[NB_ * H_];        // per-block running max
__device__ float g_bs[NB_ * H_];        // per-block running sum

// One workgroup per block n. 256 threads = 4 waves; wave w owns heads 4w..4w+3.
// Fused single pass: K rows staged once, used for both QK^T and PV (online softmax).
__global__ __launch_bounds__(256) void mla_block_kernel(
    const float* __restrict__ query,
    const float* __restrict__ key_cache,
    const float* __restrict__ block_bias,
    const int* __restrict__ block_list,
    const int* __restrict__ block_groups)
{
    __shared__ float q_s[H_ * STR];     // scaled q, 37120 B
    __shared__ float kt[16 * STR];      // current 16-row K chunk, 37120 B
    __shared__ float p_s[H_ * 16];      // p[h][s16] tile
    __shared__ float alpha_s[H_];       // per-head rescale for current chunk

    const int tid = threadIdx.x;
    const int n   = blockIdx.x;
    const int b   = block_groups[n];
    const float* K = key_cache + (long)block_list[n] * (BS_ * D_);
    const float* Q = query + (long)b * (H_ * D_);

    // ---- stage scaled q into padded LDS (16 rows x 144 float4) ----
#pragma unroll
    for (int i = 0; i < 9; ++i) {
        int flat = tid + 256 * i;           // 0..2303
        int row = flat / 144;
        int c4  = flat - row * 144;
        float4 v = *(const float4*)(Q + row * D_ + 4 * c4);
        v.x *= SCALE_; v.y *= SCALE_; v.z *= SCALE_; v.w *= SCALE_;
        *(float4*)(q_s + row * STR + 4 * c4) = v;
    }

    const int hg  = tid >> 6;    // wave id -> heads 4hg..4hg+3
    const int sl  = tid & 63;
    const int h2  = sl >> 4;     // logit-phase: head within quad
    const int s16 = sl & 15;     // logit-phase: s within chunk
    const int h   = 4 * hg + h2;

    float m_run = -1e30f;
    float l_run = 0.f;
    float4 oa0[4], oa1[4];
#pragma unroll
    for (int i = 0; i < 4; ++i) {
        oa0[i] = make_float4(0.f, 0.f, 0.f, 0.f);
        oa1[i] = make_float4(0.f, 0.f, 0.f, 0.f);
    }

    for (int sc = 0; sc < BS_; sc += 16) {
        __syncthreads();   // prev chunk's kt/p_s reads done (also guards q_s staging 1st iter)
        // ---- stage 16 K rows (coalesced; rows contiguous in global) ----
#pragma unroll
        for (int i = 0; i < 9; ++i) {
            int flat = tid + 256 * i;
            int row = flat / 144;
            int c4  = flat - row * 144;
            *(float4*)(kt + row * STR + 4 * c4) =
                *(const float4*)(K + (long)(sc + row) * D_ + 4 * c4);
        }
        __syncthreads();

        // ---- logits: lane (h, s16) computes full 576-dot ----
        float acc = 0.f;
#pragma unroll 4
        for (int d = 0; d < D_; d += 4) {
            float4 kv = *(const float4*)(kt + s16 * STR + d);
            float4 qv = *(const float4*)(q_s + h * STR + d);
            acc += qv.x * kv.x + qv.y * kv.y + qv.z * kv.z + qv.w * kv.w;
        }
        float logit = acc + block_bias[n * BS_ + sc + s16];

        // ---- online softmax update within 16-lane group (one head) ----
        float mc = logit;
#pragma unroll
        for (int off = 1; off < 16; off <<= 1) mc = fmaxf(mc, __shfl_xor(mc, off));
        float m_new = fmaxf(m_run, mc);
        float alpha = __expf(m_run - m_new);
        float p = __expf(logit - m_new);
        float psum = p;
#pragma unroll
        for (int off = 1; off < 16; off <<= 1) psum += __shfl_xor(psum, off);
        l_run = l_run * alpha + psum;
        m_run = m_new;
        p_s[h * 16 + s16] = p;
        if (s16 == 0) alpha_s[h] = alpha;
        __syncthreads();

        // ---- PV: rescale accumulators, then accumulate this chunk ----
        float a[4];
#pragma unroll
        for (int i = 0; i < 4; ++i) a[i] = alpha_s[4 * hg + i];
#pragma unroll
        for (int i = 0; i < 4; ++i) {
            oa0[i].x *= a[i]; oa0[i].y *= a[i]; oa0[i].z *= a[i]; oa0[i].w *= a[i];
            oa1[i].x *= a[i]; oa1[i].y *= a[i]; oa1[i].z *= a[i]; oa1[i].w *= a[i];
        }
#pragma unroll 4
        for (int s = 0; s < 16; ++s) {
            float4 v0 = *(const float4*)(kt + s * STR + 4 * sl);
            float4 v1 = *(const float4*)(kt + s * STR + 256 + 4 * sl);
#pragma unroll
            for (int i = 0; i < 4; ++i) {
                float pv = p_s[(4 * hg + i) * 16 + s];
                oa0[i].x += pv * v0.x; oa0[i].y += pv * v0.y;
                oa0[i].z += pv * v0.z; oa0[i].w += pv * v0.w;
                oa1[i].x += pv * v1.x; oa1[i].y += pv * v1.y;
                oa1[i].z += pv * v1.z; oa1[i].w += pv * v1.w;
            }
        }
    }

    // ---- epilogue: per-block stats + unscaled o ----
    if (s16 == 0) {
        g_bm[n * H_ + h] = m_run;
        g_bs[n * H_ + h] = l_run;
    }
    float* op = g_o + (long)n * H_ * KV_;
#pragma unroll
    for (int i = 0; i < 4; ++i) {
        *(float4*)(op + (4 * hg + i) * KV_ + 4 * sl) = oa0[i];
        *(float4*)(op + (4 * hg + i) * KV_ + 256 + 4 * sl) = oa1[i];
    }
}

// One workgroup per (b,h). Group combine: rescale each block's o and sum.
__global__ __launch_bounds__(128) void mla_combine_kernel(float* __restrict__ out)
{
    const int bh = blockIdx.x;
    const int b = bh >> 4;
    const int h = bh & 15;
    const int tid = threadIdx.x;

    float bm[16];
    float m = -1e30f;
#pragma unroll
    for (int j = 0; j < 16; ++j) {
        bm[j] = g_bm[(16 * b + j) * H_ + h];
        m = fmaxf(m, bm[j]);
    }
    float sa[16];
    float gs = 0.f;
#pragma unroll
    for (int j = 0; j < 16; ++j) {
        sa[j] = g_bs[(16 * b + j) * H_ + h] * __expf(bm[j] - m);
        gs += sa[j];
    }
    float4 acc = make_float4(0.f, 0.f, 0.f, 0.f);
#pragma unroll
    for (int j = 0; j < 16; ++j) {
        float r = __expf(bm[j] - m) / fmaxf(gs, sa[j]);
        const float4 v = *(const float4*)(g_o + ((long)((16 * b + j) * H_ + h)) * KV_ + 4 * tid);
        acc.x += r * v.x; acc.y += r * v.y;
        acc.z += r * v.z; acc.w += r * v.w;
    }
    *(float4*)(out + (long)bh * KV_ + 4 * tid) = acc;
}

extern "C" void kernel_launch(void* const* d_in, const int* in_sizes, int n_in,
                              void* d_out, int out_size, void* d_ws, size_t ws_size,
                              hipStream_t stream)
{
    const float* query        = (const float*)d_in[0];
    const float* key_cache    = (const float*)d_in[1];
    // d_in[2] = block_mapping (one-hot of block_groups) — not needed
    const float* block_bias   = (const float*)d_in[3];
    const int*   block_list   = (const int*)d_in[4];
    const int*   block_groups = (const int*)d_in[5];
    float* out = (float*)d_out;

    mla_block_kernel<<<NB_, 256, 0, stream>>>(query, key_cache, block_bias,
                                              block_list, block_groups);
    mla_combine_kernel<<<B_ * H_, 128, 0, stream>>>(out);
}